// Round 7
// baseline (758.957 us; speedup 1.0000x reference)
//
#include <hip/hip_runtime.h>

// CRF forward v7: SIXTEEN waves per sequence (1024 thr) -> 4 waves/SIMD.
// Series post-mortem: all LDS-exchange variants (v1/v2/v3/v5) show an
// invariant ~600-650 cyc/step stall regardless of LDS traffic, ring
// placement, or barriers -- they all ran 1 wave/SIMD, so the step's long
// dependency chain pays full latency per instruction with nothing to
// fill bubbles. Register-exchange (v4b/v6) is dead: compiler homes the
// 128-dword E in AGPRs (VGPR_Count 116<128 proves it). v7 keeps the
// validated v3 structure but splits the matvec over 16 waves so each
// SIMD interleaves 4 independent chains:
//   lane owns R=2 rows x C=8 cols: ONE ds_read_b128 (16 B of a),
//   8 fdot2 (two 4-deep chains), row-reduce over 16 colgroup lanes =
//   4 DPP row_ror fadd stages (colgroup = lane bits 0-3 = one DPP row;
//   rotate-reduce over disjoint segments is exact). Writer lane c==0
//   stores the pair as one b32.
// Normalizer: v3's validated stale power-of-2 feedback P = Em - P + 6,
// per-wave maxes in a 16-entry parity ring, read as one broadcast
// ds_read_b32 + 4 DPP-ror fmax (all off the recurrence chain). Exact
// integer Kacc side chain. One "s_waitcnt lgkmcnt(0); s_barrier" per
// step, no vmcnt drain (4-deep global logit prefetch stays in flight).

typedef _Float16 half_t;
typedef _Float16 h2 __attribute__((ext_vector_type(2)));

#define TB  1024
#define NUM 126
#define LBL 128

__device__ __forceinline__ float dot2f(h2 a, h2 b, float c) {
  return __builtin_amdgcn_fdot2(a, b, c, false);
}
__device__ __forceinline__ h2 bits_h2(unsigned x) {
  union { unsigned i; h2 h; } u; u.i = x; return u.h;
}
__device__ __forceinline__ unsigned h2_bits(h2 h) {
  union { unsigned i; h2 h; } u; u.h = h; return u.i;
}

template <int CTRL>
__device__ __forceinline__ float dpp_fadd(float x) {
  int xi = __float_as_int(x);
  int yi = __builtin_amdgcn_update_dpp(xi, xi, CTRL, 0xF, 0xF, false);
  return x + __int_as_float(yi);
}
template <int CTRL>
__device__ __forceinline__ float dpp_fmax(float x) {
  int xi = __float_as_int(x);
  int yi = __builtin_amdgcn_update_dpp(xi, xi, CTRL, 0xF, 0xF, false);
  return fmaxf(x, __int_as_float(yi));
}

// exact sum over the 16 lanes of a DPP row (rotate-reduce, disjoint segs)
__device__ __forceinline__ float rowsum16(float x) {
  x = dpp_fadd<0x121>(x);  // row_ror:1
  x = dpp_fadd<0x122>(x);  // row_ror:2
  x = dpp_fadd<0x124>(x);  // row_ror:4
  x = dpp_fadd<0x128>(x);  // row_ror:8
  return x;
}
// max over the 16 lanes of a DPP row
__device__ __forceinline__ float rowmax16(float x) {
  x = dpp_fmax<0x121>(x);
  x = dpp_fmax<0x122>(x);
  x = dpp_fmax<0x124>(x);
  x = dpp_fmax<0x128>(x);
  return x;
}
// max over all 64 lanes -> uniform via readlane(63)  (validated v1/v3)
__device__ __forceinline__ float wave_max64(float x) {
  x = dpp_fmax<0x111>(x);  // row_shr:1
  x = dpp_fmax<0x112>(x);  // row_shr:2
  x = dpp_fmax<0x114>(x);  // row_shr:4
  x = dpp_fmax<0x118>(x);  // row_shr:8
  x = dpp_fmax<0x142>(x);  // row_bcast:15
  x = dpp_fmax<0x143>(x);  // row_bcast:31
  return __int_as_float(__builtin_amdgcn_readlane(__float_as_int(x), 63));
}

__global__ __launch_bounds__(1024, 1)
void crf_fwd(const float* __restrict__ logits, const int* __restrict__ labels,
             const int* __restrict__ lens, const float* __restrict__ trans,
             float* __restrict__ out)
{
  const int b   = blockIdx.x;
  const int tid = threadIdx.x;
  const int wid = tid >> 6;                 // wave 0..15
  const int l   = tid & 63;                 // lane 0..63
  const int c   = l & 15;                   // colgroup 0..15 (one DPP row)
  const int g   = (wid << 2) | (l >> 4);    // row-pair 0..63
  const int r0  = 2 * g;                    // even row
  const int r1  = 2 * g + 1;                // odd row
  const float rm0 = (r0 < NUM) ? 1.0f : 0.0f;   // pair 63 (126,127): dead
  const float rm1 = (r1 < NUM) ? 1.0f : 0.0f;
  const int clb = (r0 < NUM - 1) ? r0 : (NUM - 2);   // float2-safe base
  const int len = lens[b];

  __shared__ __align__(16) h2    a_sh[2][64];   // a[par]; dword s=(a2s,a2s+1)
  __shared__ __align__(16) float ring[2][16];   // per-wave w-maxes, parity
  __shared__ float goldsh[16], Msh[16], psh[16];

  const float* lgbase = logits + (size_t)b * TB * NUM;
  const int*   lab    = labels + (size_t)b * TB;

  // ---- E = exp(trans): rows r0,r1, cols 8c..8c+7  (8 VGPRs)
  h2 E0[4], E1[4];
  {
    const float* t0 = trans + r0 * LBL + 8 * c;
    const float* t1 = trans + r1 * LBL + 8 * c;
    #pragma unroll
    for (int k = 0; k < 4; ++k) {
      h2 e0, e1;
      e0[0] = (half_t)__expf(t0[2 * k]);  e0[1] = (half_t)__expf(t0[2 * k + 1]);
      e1[0] = (half_t)__expf(t1[2 * k]);  e1[1] = (half_t)__expf(t1[2 * k + 1]);
      E0[k] = e0;  E1[k] = e1;
    }
  }

  // ---- gold score: thread t handles timestep t (T == block size)
  float gacc = 0.f;
  {
    int t = tid;
    if (t < len) {
      int lt = lab[t];
      int lp = (t == 0) ? (LBL - 2) : lab[t - 1];   // start state = 126
      gacc = lgbase[(size_t)t * NUM + lt] + trans[lt * LBL + lp];
    }
    if (tid == 0) gacc += trans[(LBL - 1) * LBL + lab[len - 1]];  // -> end
    #pragma unroll
    for (int o = 1; o < 64; o <<= 1) gacc += __shfl_xor(gacc, o);
    if (l == 0) goldsh[wid] = gacc;
  }

  // ---- a_0 = one-hot(start=126); prime ring so first P = 6
  if (tid < 64) {
    h2 ai;
    ai[0] = (half_t)((2 * tid     == LBL - 2) ? 1.0f : 0.0f);
    ai[1] = (half_t)((2 * tid + 1 == LBL - 2) ? 1.0f : 0.0f);
    a_sh[0][tid] = ai;
  }
  if (tid < 32) ring[tid >> 4][tid & 15] = 64.0f;   // Em = 6 primer
  __syncthreads();

  // ---- logit prefetch, 4 rows deep: one aligned float2 (rows r0,r1)
  float2 plg[4];
  #pragma unroll
  for (int d = 0; d < 4; ++d)
    plg[d] = *(const float2*)(lgbase + (size_t)d * NUM + clb);

  int   P = 6, Kacc = 0, Kout = 0, par = 0;
  float w0_out = 1.f, w1_out = 1.f;

  auto step = [&](float2 Qv) __attribute__((always_inline)) {
    // off-chain: ring read (broadcast b32) + 4 DPP fmax -> stale P update
    float rv = ring[par][c];
    // a-read: ONE b128 = states 8c..8c+7
    const uint4 av = *(const uint4*)((const unsigned*)&a_sh[par][0] + 4 * c);
    h2 d0 = bits_h2(av.x), d1 = bits_h2(av.y), d2 = bits_h2(av.z), d3 = bits_h2(av.w);
    float eL0 = __expf(Qv.x) * rm0;
    float eL1 = __expf(Qv.y) * rm1;
    // dots: two 4-deep chains
    float s0 = 0.f, s1 = 0.f;
    s0 = dot2f(d0, E0[0], s0);  s1 = dot2f(d0, E1[0], s1);
    s0 = dot2f(d1, E0[1], s0);  s1 = dot2f(d1, E1[1], s1);
    s0 = dot2f(d2, E0[2], s0);  s1 = dot2f(d2, E1[2], s1);
    s0 = dot2f(d3, E0[3], s0);  s1 = dot2f(d3, E1[3], s1);
    // stale P update (off-chain until sc)
    float rmax = rowmax16(rv);
    P = (((__float_as_int(rmax) >> 23) & 0xFF) - 127) - P + 6;
    // row-reduce over the 16 colgroup lanes (pure VALU, exact)
    float w0 = rowsum16(s0) * eL0;
    float w1 = rowsum16(s1) * eL1;
    float sc = __int_as_float((127 - P) << 23);   // 2^-P, EXACT
    h2 pk;
    pk[0] = (half_t)(w0 * sc);
    pk[1] = (half_t)(w1 * sc);
    if (c == 0) a_sh[par ^ 1][g] = pk;            // ds_write_b32
    Kout = Kacc;  Kacc += P;                      // exact side chain
    // per-wave w-max (groups already uniform): 2 bcast stages -> lane 63
    float wm = fmaxf(w0, w1);
    wm = dpp_fmax<0x142>(wm);                     // row_bcast:15
    wm = dpp_fmax<0x143>(wm);                     // row_bcast:31
    if (l == 63) ring[par ^ 1][wid] = wm;
    // LDS-only drain + barrier: global prefetches stay in flight
    asm volatile("s_waitcnt lgkmcnt(0)\n\ts_barrier" ::: "memory");
    w0_out = w0;  w1_out = w1;  par ^= 1;
  };

  int t = 0;
  for (; t + 4 <= len; t += 4) {
    int q0 = t + 4, q1 = t + 5, q2 = t + 6, q3 = t + 7;
    q0 = (q0 < TB) ? q0 : (TB - 1);  q1 = (q1 < TB) ? q1 : (TB - 1);
    q2 = (q2 < TB) ? q2 : (TB - 1);  q3 = (q3 < TB) ? q3 : (TB - 1);
    step(plg[0]);
    plg[0] = *(const float2*)(lgbase + (size_t)q0 * NUM + clb);
    step(plg[1]);
    plg[1] = *(const float2*)(lgbase + (size_t)q1 * NUM + clb);
    step(plg[2]);
    plg[2] = *(const float2*)(lgbase + (size_t)q2 * NUM + clb);
    step(plg[3]);
    plg[3] = *(const float2*)(lgbase + (size_t)q3 * NUM + clb);
  }
  const int rem = len - t;
  if (rem > 0) step(plg[0]);
  if (rem > 1) step(plg[1]);
  if (rem > 2) step(plg[2]);

  // ---- alpha_len[r] = Kout*ln2 + log(w_len[r]); norm = logsumexp(+trans_end)
  const float LN2 = 0.6931471805599453f;
  float K = (float)Kout * LN2;
  float v0 = K + __logf(w0_out) + trans[(LBL - 1) * LBL + r0];
  float v1 = K + __logf(w1_out) + trans[(LBL - 1) * LBL + r1];
  if (c != 0) { v0 = -__builtin_inff(); v1 = -__builtin_inff(); }  // dedupe
  float M = wave_max64(fmaxf(v0, v1));
  float p = __expf(v0 - M) + __expf(v1 - M);    // dead/-inf -> 0
  #pragma unroll
  for (int o = 1; o < 64; o <<= 1) p += __shfl_xor(p, o);
  if (l == 0) { Msh[wid] = M; psh[wid] = p; }
  __syncthreads();
  if (tid == 0) {
    float gT = 0.f, Mg = -__builtin_inff();
    #pragma unroll
    for (int i = 0; i < 16; ++i) { gT += goldsh[i]; Mg = fmaxf(Mg, Msh[i]); }
    float pg = 0.f;
    #pragma unroll
    for (int i = 0; i < 16; ++i) pg += psh[i] * __expf(Msh[i] - Mg);
    out[b] = gT - (Mg + __logf(pg));
  }
}

extern "C" void kernel_launch(void* const* d_in, const int* in_sizes, int n_in,
                              void* d_out, int out_size, void* d_ws, size_t ws_size,
                              hipStream_t stream) {
  const float* logits = (const float*)d_in[0];
  const int*   labels = (const int*)d_in[1];
  const int*   lens   = (const int*)d_in[2];
  const float* trans  = (const float*)d_in[3];
  float* out = (float*)d_out;
  (void)in_sizes; (void)n_in; (void)out_size; (void)d_ws; (void)ws_size;
  crf_fwd<<<256, 1024, 0, stream>>>(logits, labels, lens, trans, out);
}

// Round 8
// 498.281 us; speedup vs baseline: 1.5231x; 1.5231x over previous
//
#include <hip/hip_runtime.h>

// CRF forward v8: 4 waves/seq, R=4 rows x C=16 cols per lane (v5's validated
// layout), with the normalizer P computed from the READ data IN THE DOT
// SHADOW and NO max-ring at all.
// Series conclusions: lockstep waves pile up (v7, 16 waves = 1506 cyc/step);
// register-only exchange dies on E allocation (v4b/v6); the 4-wave barrier
// structure is best (v3 = 808 cyc/step) and its remaining fat is the
// max-ring round-trip + tail muls. v8: P = exponent16(max a_read) + 6,
// memoryless, computed by a 13-op pk_max/DPP tree issued AFTER the dots
// (fills the dot-chain latency) and consumed only at the tail multiply
// (eL*sc folded off-chain). Pre-barrier tail = b64 write + drain only.
//   stored_t = eL*(E . stored_{t-1}) * 2^-P_t,  Kacc += P_t,
//   alpha_t = Kacc*ln2 + log(stored_t)   (exact integer side chain).
// Per lane: 2x ds_read_b128 (16 states), 32 fdot2 (4 rows x 2 chains of 4),
// 8-lane row reduce = xor1+xor2+xor8 pure-VALU DPP (validated v5),
// writer lanes (c==0) store 4 states as one b64. One "s_waitcnt lgkmcnt(0);
// s_barrier" per step, no vmcnt drain (4-deep logit prefetch in flight).

typedef _Float16 half_t;
typedef _Float16 h2 __attribute__((ext_vector_type(2)));

#define TB  1024
#define NUM 126
#define LBL 128

__device__ __forceinline__ float dot2f(h2 a, h2 b, float c) {
  return __builtin_amdgcn_fdot2(a, b, c, false);
}
__device__ __forceinline__ h2 bits_h2(unsigned x) {
  union { unsigned i; h2 h; } u; u.i = x; return u.h;
}
__device__ __forceinline__ unsigned h2_bits(h2 h) {
  union { unsigned i; h2 h; } u; u.h = h; return u.i;
}

// packed f16 max (values >= 0, no NaN) -- VOP3P, 1 instr (validated v5)
__device__ __forceinline__ unsigned pkmax(unsigned a, unsigned b) {
  unsigned r;
  asm("v_pk_max_f16 %0, %1, %2" : "=v"(r) : "v"(a), "v"(b));
  return r;
}

template <int CTRL>
__device__ __forceinline__ float dpp_fadd(float x) {
  int xi = __float_as_int(x);
  int yi = __builtin_amdgcn_update_dpp(xi, xi, CTRL, 0xF, 0xF, false);
  return x + __int_as_float(yi);
}
template <int CTRL>
__device__ __forceinline__ float dpp_fmax(float x) {
  int xi = __float_as_int(x);
  int yi = __builtin_amdgcn_update_dpp(xi, xi, CTRL, 0xF, 0xF, false);
  return fmaxf(x, __int_as_float(yi));
}
template <int CTRL>
__device__ __forceinline__ unsigned dpp_pkmax(unsigned x) {
  unsigned y = (unsigned)__builtin_amdgcn_update_dpp((int)x, (int)x, CTRL, 0xF, 0xF, false);
  return pkmax(x, y);
}

// exact sum over 8 lanes at lane bits {0,1,3}: xor1, xor2, xor8-within-16
// (row_ror:8 within a 16-lane row is exactly l -> l^8)  (validated v5)
__device__ __forceinline__ float colsum8(float x) {
  x = dpp_fadd<0xB1>(x);    // quad_perm {1,0,3,2} = xor1
  x = dpp_fadd<0x4E>(x);    // quad_perm {2,3,0,1} = xor2
  x = dpp_fadd<0x128>(x);   // row_ror:8            = xor8
  return x;
}

// max over all 64 lanes -> lane 63 (validated v1/v3/v5)
__device__ __forceinline__ float wave_max64(float x) {
  x = dpp_fmax<0x111>(x);  // row_shr:1
  x = dpp_fmax<0x112>(x);  // row_shr:2
  x = dpp_fmax<0x114>(x);  // row_shr:4
  x = dpp_fmax<0x118>(x);  // row_shr:8
  x = dpp_fmax<0x142>(x);  // row_bcast:15
  x = dpp_fmax<0x143>(x);  // row_bcast:31
  return __int_as_float(__builtin_amdgcn_readlane(__float_as_int(x), 63));
}
// packed max over all 64 lanes -> uniform dword via readlane(63)
__device__ __forceinline__ unsigned wave_pkmax64(unsigned x) {
  x = dpp_pkmax<0x111>(x);
  x = dpp_pkmax<0x112>(x);
  x = dpp_pkmax<0x114>(x);
  x = dpp_pkmax<0x118>(x);
  x = dpp_pkmax<0x142>(x);
  x = dpp_pkmax<0x143>(x);
  return (unsigned)__builtin_amdgcn_readlane((int)x, 63);
}

__global__ __launch_bounds__(256, 1)
void crf_fwd(const float* __restrict__ logits, const int* __restrict__ labels,
             const int* __restrict__ lens, const float* __restrict__ trans,
             float* __restrict__ out)
{
  const int b   = blockIdx.x;
  const int tid = threadIdx.x;
  const int wid = tid >> 6;                       // wave 0..3
  const int l   = tid & 63;                       // lane 0..63
  const int c   = (l & 3) | ((l & 8) >> 1);       // colgroup 0..7 (bits 0,1,3)
  const int gl  = ((l >> 2) & 1) | ((l >> 3) & 6);// rowgroup lane bits (2,4,5)
  const int g   = (wid << 3) | gl;                // rowgroup 0..31
  const int row0 = g << 2;                        // rows row0..row0+3
  const bool writer = ((l & 11) == 0);            // colgroup == 0
  const float rm0 = (row0 + 0 < NUM) ? 1.0f : 0.0f;
  const float rm1 = (row0 + 1 < NUM) ? 1.0f : 0.0f;
  const float rm2 = (row0 + 2 < NUM) ? 1.0f : 0.0f;
  const float rm3 = (row0 + 3 < NUM) ? 1.0f : 0.0f;
  const int clb = (row0 <= NUM - 4) ? row0 : (NUM - 4);  // float2-safe base
  const bool sh2 = (clb != row0);                 // true only for g=31
  const int len = lens[b];

  __shared__ __align__(16) h2 a_sh[2][64];        // a[parity]; dword s=(a2s,a2s+1)
  __shared__ float goldsh[4], Msh[4], psh[4];

  const float* lgbase = logits + (size_t)b * TB * NUM;
  const int*   lab    = labels + (size_t)b * TB;

  // ---- E = exp(trans) block: rows row0..+3, cols 16c..16c+15 (32 VGPRs)
  h2 E[4][8];
  #pragma unroll
  for (int i = 0; i < 4; ++i) {
    const float* tr = trans + (row0 + i) * LBL + 16 * c;
    #pragma unroll
    for (int j = 0; j < 8; ++j) {
      h2 e;
      e[0] = (half_t)__expf(tr[2 * j]);
      e[1] = (half_t)__expf(tr[2 * j + 1]);
      E[i][j] = e;
    }
  }

  // ---- gold score (one-time, 256 threads)  (validated v5)
  float gg = 0.f;
  #pragma unroll
  for (int kk = 0; kk < 4; ++kk) {
    int t = tid + 256 * kk;
    if (t < len) {
      int lt = lab[t];
      int lp = (t == 0) ? (LBL - 2) : lab[t - 1];   // start state = 126
      gg += lgbase[(size_t)t * NUM + lt] + trans[lt * LBL + lp];
    }
  }
  if (tid == 0) gg += trans[(LBL - 1) * LBL + lab[len - 1]];  // -> end
  #pragma unroll
  for (int o = 1; o < 64; o <<= 1) gg += __shfl_xor(gg, o);
  if (l == 0) goldsh[wid] = gg;

  // ---- a_0 = one-hot(start=126): max = 1.0 -> first P = 6 automatically
  if (tid < 64) {
    h2 ai;
    ai[0] = (half_t)((2 * tid     == LBL - 2) ? 1.0f : 0.0f);
    ai[1] = (half_t)((2 * tid + 1 == LBL - 2) ? 1.0f : 0.0f);
    a_sh[0][tid] = ai;
  }
  __syncthreads();

  // ---- logit prefetch, 4 rows deep: two aligned float2 per step
  float2 pA[4], pB[4];
  #pragma unroll
  for (int d = 0; d < 4; ++d) {
    pA[d] = *(const float2*)(lgbase + (size_t)d * NUM + clb);
    pB[d] = *(const float2*)(lgbase + (size_t)d * NUM + clb + 2);
  }

  int   Kacc = 0, par = 0;
  float w0_out = 1.f, w1_out = 1.f, w2_out = 1.f, w3_out = 1.f;

  auto step = [&](float2 A, float2 B) __attribute__((always_inline)) {
    // a-read: 16 states = 2 x b128 (8-lane broadcast per address)
    const uint4* ap = (const uint4*)(&a_sh[par][8 * c]);
    uint4 u0 = ap[0], u1 = ap[1];
    h2 d0 = bits_h2(u0.x), d1 = bits_h2(u0.y), d2 = bits_h2(u0.z), d3 = bits_h2(u0.w);
    h2 d4 = bits_h2(u1.x), d5 = bits_h2(u1.y), d6 = bits_h2(u1.z), d7 = bits_h2(u1.w);
    // shadow: eL (masked rows fold to 0)
    float f0 = sh2 ? B.x : A.x;
    float f1 = sh2 ? B.y : A.y;
    float f2 = B.x, f3 = B.y;
    float eL0 = __expf(f0) * rm0;
    float eL1 = __expf(f1) * rm1;
    float eL2 = __expf(f2) * rm2;
    float eL3 = __expf(f3) * rm3;
    // dots: 4 rows x (2 chains of 4)  (validated v5)
    float s0a = 0.f, s0b = 0.f, s1a = 0.f, s1b = 0.f;
    float s2a = 0.f, s2b = 0.f, s3a = 0.f, s3b = 0.f;
    s0a = dot2f(d0, E[0][0], s0a); s0a = dot2f(d1, E[0][1], s0a);
    s0a = dot2f(d2, E[0][2], s0a); s0a = dot2f(d3, E[0][3], s0a);
    s0b = dot2f(d4, E[0][4], s0b); s0b = dot2f(d5, E[0][5], s0b);
    s0b = dot2f(d6, E[0][6], s0b); s0b = dot2f(d7, E[0][7], s0b);
    s1a = dot2f(d0, E[1][0], s1a); s1a = dot2f(d1, E[1][1], s1a);
    s1a = dot2f(d2, E[1][2], s1a); s1a = dot2f(d3, E[1][3], s1a);
    s1b = dot2f(d4, E[1][4], s1b); s1b = dot2f(d5, E[1][5], s1b);
    s1b = dot2f(d6, E[1][6], s1b); s1b = dot2f(d7, E[1][7], s1b);
    s2a = dot2f(d0, E[2][0], s2a); s2a = dot2f(d1, E[2][1], s2a);
    s2a = dot2f(d2, E[2][2], s2a); s2a = dot2f(d3, E[2][3], s2a);
    s2b = dot2f(d4, E[2][4], s2b); s2b = dot2f(d5, E[2][5], s2b);
    s2b = dot2f(d6, E[2][6], s2b); s2b = dot2f(d7, E[2][7], s2b);
    s3a = dot2f(d0, E[3][0], s3a); s3a = dot2f(d1, E[3][1], s3a);
    s3a = dot2f(d2, E[3][2], s3a); s3a = dot2f(d3, E[3][3], s3a);
    s3b = dot2f(d4, E[3][4], s3b); s3b = dot2f(d5, E[3][5], s3b);
    s3b = dot2f(d6, E[3][6], s3b); s3b = dot2f(d7, E[3][7], s3b);
    // P from the READ data, in the dot shadow (consumed only at the tail):
    // P = exponent16(max a) + 6, memoryless; stored stays in [2^-6, 2^8].
    unsigned m01 = pkmax(u0.x, u0.y), m23 = pkmax(u0.z, u0.w);
    unsigned m45 = pkmax(u1.x, u1.y), m67 = pkmax(u1.z, u1.w);
    unsigned mC  = pkmax(pkmax(m01, m23), pkmax(m45, m67));
    unsigned mb  = wave_pkmax64(mC);              // uniform dword
    int e_lo = (int)((mb >> 10) & 31), e_hi = (int)((mb >> 26) & 31);
    int m5 = (e_lo > e_hi) ? e_lo : e_hi;         // biased f16 exponent
    // sc = 2^-P = 2^-(m5-15+6) -> f32 bits (136 - m5) << 23
    float sc = __int_as_float((136 - m5) << 23);
    float e0s = eL0 * sc, e1s = eL1 * sc, e2s = eL2 * sc, e3s = eL3 * sc;
    // reduce over the 8 lanes/row (pure VALU butterfly, validated v5)
    float s0 = colsum8(s0a + s0b);
    float s1 = colsum8(s1a + s1b);
    float s2 = colsum8(s2a + s2b);
    float s3 = colsum8(s3a + s3b);
    // tail: one mul per row, pack, write
    float w0 = s0 * e0s, w1 = s1 * e1s, w2 = s2 * e2s, w3 = s3 * e3s;
    h2 pk0, pk1;
    pk0[0] = (half_t)w0;  pk0[1] = (half_t)w1;
    pk1[0] = (half_t)w2;  pk1[1] = (half_t)w3;
    if (writer) {
      uint2 pk2; pk2.x = h2_bits(pk0); pk2.y = h2_bits(pk1);
      *(uint2*)(&a_sh[par ^ 1][2 * g]) = pk2;     // ds_write_b64
    }
    Kacc += (m5 - 9);                             // exact side chain (P)
    asm volatile("s_waitcnt lgkmcnt(0)\n\ts_barrier" ::: "memory");
    w0_out = w0; w1_out = w1; w2_out = w2; w3_out = w3;
    par ^= 1;
  };

  int t = 0;
  for (; t + 4 <= len; t += 4) {
    int q0 = t + 4, q1 = t + 5, q2 = t + 6, q3 = t + 7;
    q0 = (q0 < TB) ? q0 : (TB - 1);  q1 = (q1 < TB) ? q1 : (TB - 1);
    q2 = (q2 < TB) ? q2 : (TB - 1);  q3 = (q3 < TB) ? q3 : (TB - 1);
    step(pA[0], pB[0]);
    pA[0] = *(const float2*)(lgbase + (size_t)q0 * NUM + clb);
    pB[0] = *(const float2*)(lgbase + (size_t)q0 * NUM + clb + 2);
    step(pA[1], pB[1]);
    pA[1] = *(const float2*)(lgbase + (size_t)q1 * NUM + clb);
    pB[1] = *(const float2*)(lgbase + (size_t)q1 * NUM + clb + 2);
    step(pA[2], pB[2]);
    pA[2] = *(const float2*)(lgbase + (size_t)q2 * NUM + clb);
    pB[2] = *(const float2*)(lgbase + (size_t)q2 * NUM + clb + 2);
    step(pA[3], pB[3]);
    pA[3] = *(const float2*)(lgbase + (size_t)q3 * NUM + clb);
    pB[3] = *(const float2*)(lgbase + (size_t)q3 * NUM + clb + 2);
  }
  const int rem = len - t;
  if (rem > 0) step(pA[0], pB[0]);
  if (rem > 1) step(pA[1], pB[1]);
  if (rem > 2) step(pA[2], pB[2]);

  // ---- alpha_len[r] = Kacc*ln2 + log(stored_len[r]); norm = lse(+trans_end)
  const float LN2 = 0.6931471805599453f;
  float K = (float)Kacc * LN2;
  float vv0 = K + __logf(w0_out) + trans[(LBL - 1) * LBL + row0 + 0];
  float vv1 = K + __logf(w1_out) + trans[(LBL - 1) * LBL + row0 + 1];
  float vv2 = K + __logf(w2_out) + trans[(LBL - 1) * LBL + row0 + 2];
  float vv3 = K + __logf(w3_out) + trans[(LBL - 1) * LBL + row0 + 3];
  if (!writer) {                                   // dedupe the 8 replicas
    vv0 = vv1 = vv2 = vv3 = -__builtin_inff();
  }
  float vm = fmaxf(fmaxf(vv0, vv1), fmaxf(vv2, vv3));
  float M = wave_max64(vm);
  float p = __expf(vv0 - M) + __expf(vv1 - M) + __expf(vv2 - M) + __expf(vv3 - M);
  #pragma unroll
  for (int o = 1; o < 64; o <<= 1) p += __shfl_xor(p, o);
  if (l == 0) { Msh[wid] = M; psh[wid] = p; }
  __syncthreads();
  if (tid == 0) {
    float gT = goldsh[0] + goldsh[1] + goldsh[2] + goldsh[3];
    float Mg = fmaxf(fmaxf(Msh[0], Msh[1]), fmaxf(Msh[2], Msh[3]));
    float pg = psh[0] * __expf(Msh[0] - Mg) + psh[1] * __expf(Msh[1] - Mg)
             + psh[2] * __expf(Msh[2] - Mg) + psh[3] * __expf(Msh[3] - Mg);
    out[b] = gT - (Mg + __logf(pg));
  }
}

extern "C" void kernel_launch(void* const* d_in, const int* in_sizes, int n_in,
                              void* d_out, int out_size, void* d_ws, size_t ws_size,
                              hipStream_t stream) {
  const float* logits = (const float*)d_in[0];
  const int*   labels = (const int*)d_in[1];
  const int*   lens   = (const int*)d_in[2];
  const float* trans  = (const float*)d_in[3];
  float* out = (float*)d_out;
  (void)in_sizes; (void)n_in; (void)out_size; (void)d_ws; (void)ws_size;
  crf_fwd<<<256, 256, 0, stream>>>(logits, labels, lens, trans, out);
}